// Round 3
// baseline (159.301 us; speedup 1.0000x reference)
//
#include <hip/hip_runtime.h>

// Masked embedding gather:
//   idx = x[i]; if (idx % 2 == 0) idx = 0;  out[i, :] = emb[idx, :]
// x: (8, 4096) int32, emb: (50257, 512) fp32, out: (8, 4096, 512) fp32.
//
// One 64-lane wave per 4 tokens. Per token: 512 floats = 128 float4
// = 64 lanes x 2. All 4 index loads issue first, then all 8 gather
// float4 loads are in flight before any store (4x the MLP of the
// 1-token/wave version). Output stores are non-temporal: write-only
// data shouldn't evict the 103 MB emb table from L2/Infinity-Cache
// (it fits entirely in the 256 MB L3).
//
// Note: __builtin_nontemporal_store requires a native vector type, not
// HIP's float4 class -> use ext_vector_type(4).

#define EMB 512
#define TOK_PER_WAVE 4

typedef float f32x4 __attribute__((ext_vector_type(4)));

__global__ __launch_bounds__(256) void embed_gather_kernel(
    const int* __restrict__ x,
    const float* __restrict__ emb,
    float* __restrict__ out,
    int n_tokens)
{
    const int lane = threadIdx.x & 63;
    const int wave = (blockIdx.x * blockDim.x + threadIdx.x) >> 6;
    const int tok_base = wave * TOK_PER_WAVE;
    if (tok_base >= n_tokens) return;

    // Index loads first (n_tokens is a multiple of TOK_PER_WAVE).
    int idx[TOK_PER_WAVE];
#pragma unroll
    for (int t = 0; t < TOK_PER_WAVE; ++t) {
        int id = x[tok_base + t];
        idx[t] = (id & 1) ? id : 0;   // even ids -> row 0 (ids non-negative)
    }

    // Issue all gather loads before any store: 8 dwordx4 loads in flight.
    f32x4 a[TOK_PER_WAVE], b[TOK_PER_WAVE];
#pragma unroll
    for (int t = 0; t < TOK_PER_WAVE; ++t) {
        const f32x4* __restrict__ src =
            (const f32x4*)(emb + (size_t)idx[t] * EMB);
        a[t] = src[lane];
        b[t] = src[lane + 64];
    }

#pragma unroll
    for (int t = 0; t < TOK_PER_WAVE; ++t) {
        f32x4* __restrict__ dst =
            (f32x4*)(out + (size_t)(tok_base + t) * EMB);
        __builtin_nontemporal_store(a[t], dst + lane);
        __builtin_nontemporal_store(b[t], dst + lane + 64);
    }
}

extern "C" void kernel_launch(void* const* d_in, const int* in_sizes, int n_in,
                              void* d_out, int out_size, void* d_ws, size_t ws_size,
                              hipStream_t stream)
{
    const int* x = (const int*)d_in[0];          // (8, 4096) int32
    const float* emb = (const float*)d_in[1];    // (50257, 512) fp32
    float* out = (float*)d_out;                  // (8, 4096, 512) fp32

    const int n_tokens = in_sizes[0];            // 32768
    const int tokens_per_block = (256 / 64) * TOK_PER_WAVE;   // 16
    const int blocks = (n_tokens + tokens_per_block - 1) / tokens_per_block;

    embed_gather_kernel<<<blocks, 256, 0, stream>>>(x, emb, out, n_tokens);
}